// Round 1
// baseline (54.563 us; speedup 1.0000x reference)
//
#include <hip/hip_runtime.h>

// Camera ISP pipeline fused: mosaic -> 3x3 gauss blur -> per-channel 17-knot
// LUT interp -> +noise -> sparse 5x5 demosaic -> bayer-parity select -> clip.
// Single kernel, LDS-staged tiles.

#define TX 64
#define TY 16
#define BH (TY + 6)    // bayer tile height (halo 3)
#define BW (TX + 6)    // 70
#define BSTR (BW + 2)  // 72, LDS row stride
#define NH (TY + 4)    // noisy tile height (halo 2)
#define NW (TX + 4)    // 68
#define NSTR (NW + 4)  // 72

__device__ __forceinline__ int refl(int i, int n) {
    return i < 0 ? -i : (i >= n ? 2 * n - 2 - i : i);
}

__global__ __launch_bounds__(256) void camera_kernel(
    const float* __restrict__ im, const float* __restrict__ yp,
    const float* __restrict__ noise, float* __restrict__ out,
    int H, int W)
{
    __shared__ float s_bayer[BH * BSTR];
    __shared__ float s_noisy[NH * NSTR];
    __shared__ float s_yp[3][17];

    const int b   = blockIdx.z;
    const int gy0 = blockIdx.y * TY;
    const int gx0 = blockIdx.x * TX;
    const int tid = threadIdx.x;

    if (tid < 51) s_yp[tid / 17][tid % 17] = yp[tid];

    const size_t HW = (size_t)H * W;
    const float* imb = im + (size_t)b * 3 * HW;
    const float* nzb = noise + (size_t)b * HW;

    // ---- Stage A: reflect-extended bayer tile (halo 3) ----
    for (int idx = tid; idx < BH * BW; idx += 256) {
        int ly = idx / BW, lx = idx - ly * BW;
        int py = gy0 + ly - 3, px = gx0 + lx - 3;
        int y = refl(py, H), x = refl(px, W);
        int c = 1 + (x & 1) - (y & 1);   // CMAP[[1,2],[0,1]]
        s_bayer[ly * BSTR + lx] = imb[(size_t)c * HW + (size_t)y * W + x] * 255.0f;
    }
    __syncthreads();

    // ---- Stage B: noisy tile (halo 2): blur -> interp -> +noise ----
    const float kC = 0.84497316f;   // center of 3x3 gauss(sigma=0.4), normalized
    const float kE = 0.03712550f;   // edge
    const float kK = 0.00163118f;   // corner
    for (int idx = tid; idx < NH * NW; idx += 256) {
        int ly = idx / NW, lx = idx - ly * NW;
        int py = gy0 + ly - 2, px = gx0 + lx - 2;
        const float* bp = &s_bayer[(ly + 1) * BSTR + (lx + 1)];
        float blurred =
            kK * (bp[-BSTR - 1] + bp[-BSTR + 1] + bp[BSTR - 1] + bp[BSTR + 1]) +
            kE * (bp[-BSTR] + bp[BSTR] + bp[-1] + bp[1]) +
            kC * bp[0];
        int c = 1 + (px & 1) - (py & 1);   // parity preserved under reflect
        float s = blurred * (16.0f / 255.0f);   // uniform knots, spacing 255/16
        int i = (int)s;
        i = i < 0 ? 0 : (i > 15 ? 15 : i);
        float fr = s - (float)i;
        float y0 = s_yp[c][i];
        float lin = y0 + fr * (s_yp[c][i + 1] - y0);
        int y = refl(py, H), x = refl(px, W);
        s_noisy[ly * NSTR + lx] = lin + nzb[(size_t)y * W + x];
    }
    __syncthreads();

    // ---- Stage C: sparse 5x5 demosaic + parity select + clip ----
    const int tx = tid & 63;
    const int ty = tid >> 6;
    const size_t outb = (size_t)b * 3 * HW;
    const float invs = 1.0f / 255.0f;
    for (int r = ty; r < TY; r += 4) {
        int py = gy0 + r, px = gx0 + tx;
        const float* np_ = &s_noisy[(r + 2) * NSTR + (tx + 2)];
        float ctr  = np_[0];
        float ax1y = np_[-NSTR] + np_[NSTR];
        float ax1x = np_[-1] + np_[1];
        float ax2y = np_[-2 * NSTR] + np_[2 * NSTR];
        float ax2x = np_[-2] + np_[2];
        float diag = np_[-NSTR - 1] + np_[-NSTR + 1] + np_[NSTR - 1] + np_[NSTR + 1];

        float g = (2.0f * (ax1y + ax1x) - ax2y - ax2x + 4.0f * ctr) * 0.125f;
        float h = (0.5f * ax2y - diag - ax2x + 4.0f * ax1x + 5.0f * ctr) * 0.125f;
        float v = (0.5f * ax2x - diag - ax2y + 4.0f * ax1y + 5.0f * ctr) * 0.125f;
        float d = (2.0f * diag - 1.5f * (ax2y + ax2x) + 6.0f * ctr) * 0.125f;

        bool p00 = !(py & 1) && !(px & 1);
        bool p01 = !(py & 1) &&  (px & 1);
        bool p10 =  (py & 1) && !(px & 1);
        bool p11 =  (py & 1) &&  (px & 1);

        float R  = p10 ? ctr : (p11 ? h : (p00 ? v : d));
        float G  = (p00 || p11) ? ctr : g;
        float Bv = p01 ? ctr : (p00 ? h : (p11 ? v : d));

        size_t o = outb + (size_t)py * W + px;
        out[o]          = fminf(fmaxf(R * invs, 0.f), 1.f);
        out[o + HW]     = fminf(fmaxf(G * invs, 0.f), 1.f);
        out[o + 2 * HW] = fminf(fmaxf(Bv * invs, 0.f), 1.f);
    }
}

extern "C" void kernel_launch(void* const* d_in, const int* in_sizes, int n_in,
                              void* d_out, int out_size, void* d_ws, size_t ws_size,
                              hipStream_t stream) {
    const float* im    = (const float*)d_in[0];
    const float* yp    = (const float*)d_in[1];
    const float* noise = (const float*)d_in[2];
    float* out = (float*)d_out;

    const int H = 512, W = 512;
    const int B = in_sizes[2] / (H * W);   // noise is (B,1,H,W)

    dim3 grid(W / TX, H / TY, B);
    camera_kernel<<<grid, 256, 0, stream>>>(im, yp, noise, out, H, W);
}

// Round 2
// 52.695 us; speedup vs baseline: 1.0354x; 1.0354x over previous
//
#include <hip/hip_runtime.h>

// Camera ISP fused: mosaic -> 3x3 gauss blur -> 17-knot LUT -> +noise ->
// sparse 5x5 demosaic -> bayer-parity select -> clip.
// Round 1: float4 vectorization of all global/LDS traffic, 64x32 tiles.

#define TX 64
#define TY 32
#define BROWS (TY + 6)     // 38 bayer rows (halo 3)
#define BCOL4 20           // 20 float4 = 80 cols, origin x = gx0-8
#define BSTR  80           // floats per bayer LDS row
#define NROWS (TY + 4)     // 36 noisy rows (halo 2)
#define NCOL4 18           // 18 float4 = 72 cols, origin x = gx0-4
#define NSTR  72

__device__ __forceinline__ int refl(int i, int n) {
    return i < 0 ? -i : (i >= n ? 2 * n - 2 - i : i);
}

__global__ __launch_bounds__(256) void camera_kernel(
    const float* __restrict__ im, const float* __restrict__ yp,
    const float* __restrict__ noise, float* __restrict__ out,
    int H, int W)
{
    __shared__ float s_bayer[BROWS * BSTR];   // 12160 B
    __shared__ float s_noisy[NROWS * NSTR];   // 10368 B
    __shared__ float s_yp[3][17];

    const int b   = blockIdx.z;
    const int gy0 = blockIdx.y * TY;
    const int gx0 = blockIdx.x * TX;
    const int tid = threadIdx.x;

    if (tid < 51) s_yp[tid / 17][tid % 17] = yp[tid];

    const size_t HW = (size_t)H * W;
    const float* imb = im + (size_t)b * 3 * HW;
    const float* nzb = noise + (size_t)b * HW;

    // ---- Stage A: bayer tile (x255), reflect-extended, float4 staged ----
    for (int idx = tid; idx < BROWS * BCOL4; idx += 256) {
        int r  = idx / BCOL4;
        int c4 = idx - r * BCOL4;
        int py = gy0 + r - 3;
        int y  = refl(py, H);                  // parity-preserving
        int px4 = gx0 - 8 + 4 * c4;
        int chLo = (py & 1) ? 0 : 1;           // cmap: even row (1,2), odd (0,1)
        const float* pl = imb + (size_t)chLo * HW + (size_t)y * W;
        const float* ph = pl + HW;
        float4 v;
        if (px4 >= 0 && px4 + 3 < W) {
            float4 a  = *(const float4*)(pl + px4);
            float4 bq = *(const float4*)(ph + px4);
            v = make_float4(a.x, bq.y, a.z, bq.w);   // x-parity select
        } else {
            float t0, t1, t2, t3;
            int x0 = refl(px4 + 0, W); t0 = ((px4 + 0) & 1) ? ph[x0] : pl[x0];
            int x1 = refl(px4 + 1, W); t1 = ((px4 + 1) & 1) ? ph[x1] : pl[x1];
            int x2 = refl(px4 + 2, W); t2 = ((px4 + 2) & 1) ? ph[x2] : pl[x2];
            int x3 = refl(px4 + 3, W); t3 = ((px4 + 3) & 1) ? ph[x3] : pl[x3];
            v = make_float4(t0, t1, t2, t3);
        }
        v.x *= 255.0f; v.y *= 255.0f; v.z *= 255.0f; v.w *= 255.0f;
        *(float4*)&s_bayer[r * BSTR + 4 * c4] = v;
    }
    __syncthreads();

    // ---- Stage B: noisy tile = interp(blur(bayer)) + noise, 4/thread ----
    const float g0 = 0.04038794f;   // 1D gauss tail (sigma=0.4, normalized)
    const float g1 = 0.91922413f;   // 1D gauss center
    for (int idx = tid; idx < NROWS * NCOL4; idx += 256) {
        int r  = idx / NCOL4;
        int c4 = idx - r * NCOL4;
        int py = gy0 + r - 2;
        // bayer tile rows r..r+2 = global py-1..py+1; cols 4c4+3..4c4+8 needed
        const float* rb = &s_bayer[r * BSTR + 4 * c4];
        float4 a0 = *(const float4*)(rb);
        float4 a1 = *(const float4*)(rb + 4);
        float4 a2 = *(const float4*)(rb + 8);
        float4 b0 = *(const float4*)(rb + BSTR);
        float4 b1 = *(const float4*)(rb + BSTR + 4);
        float4 b2 = *(const float4*)(rb + BSTR + 8);
        float4 c0 = *(const float4*)(rb + 2 * BSTR);
        float4 c1 = *(const float4*)(rb + 2 * BSTR + 4);
        float4 c2 = *(const float4*)(rb + 2 * BSTR + 8);
        // vertical blur, cols +3..+8
        float v0 = fmaf(g0, a0.w + c0.w, g1 * b0.w);
        float v1 = fmaf(g0, a1.x + c1.x, g1 * b1.x);
        float v2 = fmaf(g0, a1.y + c1.y, g1 * b1.y);
        float v3 = fmaf(g0, a1.z + c1.z, g1 * b1.z);
        float v4 = fmaf(g0, a1.w + c1.w, g1 * b1.w);
        float v5 = fmaf(g0, a2.x + c2.x, g1 * b2.x);
        // horizontal blur -> 4 outputs
        float bl0 = fmaf(g0, v0 + v2, g1 * v1);
        float bl1 = fmaf(g0, v1 + v3, g1 * v2);
        float bl2 = fmaf(g0, v2 + v4, g1 * v3);
        float bl3 = fmaf(g0, v3 + v5, g1 * v4);

        int chLo = (py & 1) ? 0 : 1;
        int chHi = chLo + 1;
        float lin0, lin1, lin2, lin3;
        {
            float s = bl0 * (16.0f / 255.0f);
            int i = (int)s; i = i < 0 ? 0 : (i > 15 ? 15 : i);
            float y0 = s_yp[chLo][i];
            lin0 = fmaf(s - (float)i, s_yp[chLo][i + 1] - y0, y0);
        }
        {
            float s = bl1 * (16.0f / 255.0f);
            int i = (int)s; i = i < 0 ? 0 : (i > 15 ? 15 : i);
            float y0 = s_yp[chHi][i];
            lin1 = fmaf(s - (float)i, s_yp[chHi][i + 1] - y0, y0);
        }
        {
            float s = bl2 * (16.0f / 255.0f);
            int i = (int)s; i = i < 0 ? 0 : (i > 15 ? 15 : i);
            float y0 = s_yp[chLo][i];
            lin2 = fmaf(s - (float)i, s_yp[chLo][i + 1] - y0, y0);
        }
        {
            float s = bl3 * (16.0f / 255.0f);
            int i = (int)s; i = i < 0 ? 0 : (i > 15 ? 15 : i);
            float y0 = s_yp[chHi][i];
            lin3 = fmaf(s - (float)i, s_yp[chHi][i + 1] - y0, y0);
        }

        int y = refl(py, H);
        int px4 = gx0 - 4 + 4 * c4;
        float4 nz;
        if (px4 >= 0 && px4 + 3 < W) {
            nz = *(const float4*)(nzb + (size_t)y * W + px4);
        } else {
            const float* nr = nzb + (size_t)y * W;
            nz = make_float4(nr[refl(px4 + 0, W)], nr[refl(px4 + 1, W)],
                             nr[refl(px4 + 2, W)], nr[refl(px4 + 3, W)]);
        }
        *(float4*)&s_noisy[r * NSTR + 4 * c4] =
            make_float4(lin0 + nz.x, lin1 + nz.y, lin2 + nz.z, lin3 + nz.w);
    }
    __syncthreads();

    // ---- Stage C: sparse 5x5 demosaic + parity select + clip, 4/thread ----
    const size_t outb = (size_t)b * 3 * HW;
    const float invs = 1.0f / 255.0f;
    #pragma unroll
    for (int it = 0; it < 2; ++it) {
        int r   = (tid >> 4) + it * 16;      // 0..31
        int c4  = tid & 15;
        int py  = gy0 + r;
        int pr  = r + 2;
        const float* nb = &s_noisy[pr * NSTR + 4 * c4];
        float4 m0 = *(const float4*)(nb);            // cols +0..+3 (use +2,+3)
        float4 m1 = *(const float4*)(nb + 4);        // +4..+7
        float4 m2 = *(const float4*)(nb + 8);        // +8..+11 (use +8,+9)
        float4 ua = *(const float4*)(nb - NSTR);
        float4 ub = *(const float4*)(nb - NSTR + 4);
        float4 uc = *(const float4*)(nb - NSTR + 8);
        float4 da = *(const float4*)(nb + NSTR);
        float4 db = *(const float4*)(nb + NSTR + 4);
        float4 dc = *(const float4*)(nb + NSTR + 8);
        float4 tu = *(const float4*)(nb - 2 * NSTR + 4);
        float4 td = *(const float4*)(nb + 2 * NSTR + 4);

        float m[8]  = {m0.z, m0.w, m1.x, m1.y, m1.z, m1.w, m2.x, m2.y}; // +2..+9
        float uu[6] = {ua.w, ub.x, ub.y, ub.z, ub.w, uc.x};             // +3..+8
        float dd[6] = {da.w, db.x, db.y, db.z, db.w, dc.x};
        float tuu[4] = {tu.x, tu.y, tu.z, tu.w};                        // +4..+7
        float tdd[4] = {td.x, td.y, td.z, td.w};

        float Rv[4], Gv[4], Bv[4];
        bool pyOdd = (py & 1) != 0;
        #pragma unroll
        for (int i = 0; i < 4; ++i) {
            float ctr  = m[i + 2];
            float ax1x = m[i + 1] + m[i + 3];
            float ax2x = m[i] + m[i + 4];
            float ax1y = uu[i + 1] + dd[i + 1];
            float diag = uu[i] + uu[i + 2] + dd[i] + dd[i + 2];
            float ax2y = tuu[i] + tdd[i];

            float g = (2.0f * (ax1y + ax1x) - ax2y - ax2x + 4.0f * ctr) * 0.125f;
            float h = (0.5f * ax2y - diag - ax2x + 4.0f * ax1x + 5.0f * ctr) * 0.125f;
            float v = (0.5f * ax2x - diag - ax2y + 4.0f * ax1y + 5.0f * ctr) * 0.125f;
            float d = (2.0f * diag - 1.5f * (ax2y + ax2x) + 6.0f * ctr) * 0.125f;

            float R, G, B;
            if ((i & 1) == 0) {   // x even
                R = pyOdd ? ctr : v;
                G = pyOdd ? g   : ctr;
                B = pyOdd ? d   : h;
            } else {              // x odd
                R = pyOdd ? h   : d;
                G = pyOdd ? ctr : g;
                B = pyOdd ? v   : ctr;
            }
            Rv[i] = fminf(fmaxf(R * invs, 0.0f), 1.0f);
            Gv[i] = fminf(fmaxf(G * invs, 0.0f), 1.0f);
            Bv[i] = fminf(fmaxf(B * invs, 0.0f), 1.0f);
        }

        size_t o = outb + (size_t)py * W + (gx0 + 4 * c4);
        *(float4*)(out + o)          = make_float4(Rv[0], Rv[1], Rv[2], Rv[3]);
        *(float4*)(out + o + HW)     = make_float4(Gv[0], Gv[1], Gv[2], Gv[3]);
        *(float4*)(out + o + 2 * HW) = make_float4(Bv[0], Bv[1], Bv[2], Bv[3]);
    }
}

extern "C" void kernel_launch(void* const* d_in, const int* in_sizes, int n_in,
                              void* d_out, int out_size, void* d_ws, size_t ws_size,
                              hipStream_t stream) {
    const float* im    = (const float*)d_in[0];
    const float* yp    = (const float*)d_in[1];
    const float* noise = (const float*)d_in[2];
    float* out = (float*)d_out;

    const int H = 512, W = 512;
    const int B = in_sizes[2] / (H * W);   // noise is (B,1,H,W)

    dim3 grid(W / TX, H / TY, B);
    camera_kernel<<<grid, 256, 0, stream>>>(im, yp, noise, out, H, W);
}

// Round 3
// 50.753 us; speedup vs baseline: 1.0751x; 1.0383x over previous
//
#include <hip/hip_runtime.h>

// Camera ISP fused: mosaic -> 3x3 gauss blur -> 17-knot LUT -> +noise ->
// sparse 5x5 demosaic -> bayer-parity select -> clip.
// Round 2: conflict-free LDS strides (76/84), row-pair processing with
// compile-time parity (only 2 demosaic filters per pixel), float2 LUT.

#define TX 64
#define TY 32
#define BROWS 38       // bayer rows: gy0-3 .. gy0+34
#define BSTRIDE 84     // floats; 84%32=20 -> row starts spread over 8 bank quads
#define NROWS 36       // noisy rows: gy0-2 .. gy0+33
#define NSTRIDE 76     // 76%32=12 -> conflict-free stage C

__device__ __forceinline__ int refl(int i, int n) {
    return i < 0 ? -i : (i >= n ? 2 * n - 2 - i : i);
}

__device__ __forceinline__ float interp1(float bl, const float2* tab) {
    float s = bl * (16.0f / 255.0f);
    int i = (int)s;
    i = i > 15 ? 15 : i;
    float2 p = tab[i];
    return fmaf(s - (float)i, p.y - p.x, p.x);
}

__device__ __forceinline__ float clip01(float x) {
    return fminf(fmaxf(x * (1.0f / 255.0f), 0.0f), 1.0f);
}

__global__ __launch_bounds__(256) void camera_kernel(
    const float* __restrict__ im, const float* __restrict__ yp,
    const float* __restrict__ noise, float* __restrict__ out,
    int H, int W)
{
    __shared__ float s_bayer[BROWS * BSTRIDE];   // 12768 B
    __shared__ float s_noisy[NROWS * NSTRIDE];   // 10944 B
    __shared__ float2 s_tab[3][16];              // 384 B

    const int b   = blockIdx.z;
    const int gy0 = blockIdx.y * TY;   // even
    const int gx0 = blockIdx.x * TX;   // even
    const int tid = threadIdx.x;

    if (tid < 48) {
        int ch = tid >> 4, i = tid & 15;
        s_tab[ch][i] = make_float2(yp[ch * 17 + i], yp[ch * 17 + i + 1]);
    }

    const size_t HW = (size_t)H * W;
    const float* imb = im + (size_t)b * 3 * HW;
    const float* nzb = noise + (size_t)b * HW;

    // ---- Stage A: bayer tile (x255), cols gx0-8..gx0+71 (80), reflect-ext ----
    for (int idx = tid; idx < BROWS * 20; idx += 256) {
        int r = idx / 20, j = idx - r * 20;
        int py = gy0 + r - 3;
        int y  = refl(py, H);                     // parity-preserving
        int px4 = gx0 - 8 + 4 * j;
        int chLo = (py & 1) ? 0 : 1;              // CMAP[[1,2],[0,1]]
        const float* pl = imb + (size_t)chLo * HW + (size_t)y * W;
        const float* ph = pl + HW;
        float4 v;
        if (px4 >= 0 && px4 + 3 < W) {
            float4 a  = *(const float4*)(pl + px4);
            float4 bq = *(const float4*)(ph + px4);
            v = make_float4(a.x, bq.y, a.z, bq.w);   // x-parity select (px4 even)
        } else {
            int x0 = refl(px4 + 0, W); float t0 = ((px4 + 0) & 1) ? ph[x0] : pl[x0];
            int x1 = refl(px4 + 1, W); float t1 = ((px4 + 1) & 1) ? ph[x1] : pl[x1];
            int x2 = refl(px4 + 2, W); float t2 = ((px4 + 2) & 1) ? ph[x2] : pl[x2];
            int x3 = refl(px4 + 3, W); float t3 = ((px4 + 3) & 1) ? ph[x3] : pl[x3];
            v = make_float4(t0, t1, t2, t3);
        }
        v.x *= 255.0f; v.y *= 255.0f; v.z *= 255.0f; v.w *= 255.0f;
        *(float4*)&s_bayer[r * BSTRIDE + 4 * j] = v;
    }
    __syncthreads();

    // ---- Stage B: noisy row-pairs = interp(blur(bayer)) + noise ----
    // 18 row-pairs x 18 col-chunks; noisy cols gx0-4..gx0+67 (72)
    const float g0 = 0.04038794f;
    const float g1 = 0.91922413f;
    for (int idx = tid; idx < 18 * 18; idx += 256) {
        int rp = idx / 18, c4 = idx - rp * 18;
        int py0 = gy0 - 2 + 2 * rp;               // even row
        // bayer rows 2rp..2rp+3 = global py0-1..py0+2; window idx 4c4..4c4+11
        const float* rb = &s_bayer[(2 * rp) * BSTRIDE + 4 * c4];
        float q[4][12];
        #pragma unroll
        for (int rr = 0; rr < 4; ++rr) {
            const float* p = rb + rr * BSTRIDE;
            *(float4*)&q[rr][0] = *(const float4*)(p);
            *(float4*)&q[rr][4] = *(const float4*)(p + 4);
            *(float4*)&q[rr][8] = *(const float4*)(p + 8);
        }
        // needed bayer span: positions 3..8 (global cols g0-1..g0+4 for 4 px)
        float t0[6], t1[6];
        #pragma unroll
        for (int k = 0; k < 6; ++k) {
            float a = q[0][3 + k], bb = q[1][3 + k], c = q[2][3 + k], d = q[3][3 + k];
            t0[k] = fmaf(g0, a + c,  g1 * bb);   // vblur for row py0
            t1[k] = fmaf(g0, bb + d, g1 * c);    // vblur for row py0+1
        }
        // noise loads (reflect rows; cols aligned except block edges)
        int y0r = refl(py0, H), y1r = refl(py0 + 1, H);
        int px4n = gx0 - 4 + 4 * c4;
        float4 nz0, nz1;
        if (px4n >= 0 && px4n + 3 < W) {
            nz0 = *(const float4*)(nzb + (size_t)y0r * W + px4n);
            nz1 = *(const float4*)(nzb + (size_t)y1r * W + px4n);
        } else {
            const float* n0 = nzb + (size_t)y0r * W;
            const float* n1 = nzb + (size_t)y1r * W;
            int xa = refl(px4n, W), xb = refl(px4n + 1, W),
                xc = refl(px4n + 2, W), xd = refl(px4n + 3, W);
            nz0 = make_float4(n0[xa], n0[xb], n0[xc], n0[xd]);
            nz1 = make_float4(n1[xa], n1[xb], n1[xc], n1[xd]);
        }
        float o0[4], o1[4];
        #pragma unroll
        for (int i = 0; i < 4; ++i) {
            float bl0 = fmaf(g0, t0[i] + t0[i + 2], g1 * t0[i + 1]);
            float bl1 = fmaf(g0, t1[i] + t1[i + 2], g1 * t1[i + 1]);
            // even row: x even -> ch1, x odd -> ch2 ; odd row: ch0 / ch1
            o0[i] = interp1(bl0, s_tab[(i & 1) ? 2 : 1]);
            o1[i] = interp1(bl1, s_tab[(i & 1) ? 1 : 0]);
        }
        *(float4*)&s_noisy[(2 * rp) * NSTRIDE + 4 * c4] =
            make_float4(o0[0] + nz0.x, o0[1] + nz0.y, o0[2] + nz0.z, o0[3] + nz0.w);
        *(float4*)&s_noisy[(2 * rp + 1) * NSTRIDE + 4 * c4] =
            make_float4(o1[0] + nz1.x, o1[1] + nz1.y, o1[2] + nz1.z, o1[3] + nz1.w);
    }
    __syncthreads();

    // ---- Stage C: demosaic, 2 output rows x 4 cols per thread ----
    const int rp = tid >> 4;      // 0..15
    const int c4 = tid & 15;      // 0..15
    const int nbase = (2 * rp + 2) * NSTRIDE + 4 * c4;
    float w[4][12];               // noisy rows 2rp+1 .. 2rp+4, cols idx 4c4..+11
    #pragma unroll
    for (int rr = 0; rr < 4; ++rr) {
        const float* p = &s_noisy[nbase + (rr - 1) * NSTRIDE];
        *(float4*)&w[rr][0] = *(const float4*)(p);
        *(float4*)&w[rr][4] = *(const float4*)(p + 4);
        *(float4*)&w[rr][8] = *(const float4*)(p + 8);
    }
    float4 c2u = *(const float4*)&s_noisy[nbase - 2 * NSTRIDE + 4];  // row 2rp, centers
    float4 c2d = *(const float4*)&s_noisy[nbase + 3 * NSTRIDE + 4];  // row 2rp+5, centers
    float cu[4] = {c2u.x, c2u.y, c2u.z, c2u.w};
    float cd[4] = {c2d.x, c2d.y, c2d.z, c2d.w};

    float R0[4], G0[4], B0[4], R1[4], G1[4], B1[4];

    auto dem = [&](const float (&up)[12], const float (&ct)[12], const float (&dn)[12],
                   const float* u2, const float* d2, bool rowOdd,
                   float* R, float* G, float* Bv) {
        #pragma unroll
        for (int i = 0; i < 4; ++i) {
            float c    = ct[4 + i];
            float ax1x = ct[3 + i] + ct[5 + i];
            float ax2x = ct[2 + i] + ct[6 + i];
            float ax1y = up[4 + i] + dn[4 + i];
            float diag = up[3 + i] + up[5 + i] + dn[3 + i] + dn[5 + i];
            float ax2y = u2[i] + d2[i];
            const bool xOdd = (i & 1) != 0;
            if (!xOdd && !rowOdd) {          // p00: R=v, G=raw, B=h
                float h = (0.5f * ax2y - diag - ax2x + 4.0f * ax1x + 5.0f * c) * 0.125f;
                float v = (0.5f * ax2x - diag - ax2y + 4.0f * ax1y + 5.0f * c) * 0.125f;
                R[i] = v; G[i] = c; Bv[i] = h;
            } else if (xOdd && !rowOdd) {    // p01: R=d, G=g, B=raw
                float g = (2.0f * (ax1y + ax1x) - ax2y - ax2x + 4.0f * c) * 0.125f;
                float d = (2.0f * diag - 1.5f * (ax2y + ax2x) + 6.0f * c) * 0.125f;
                R[i] = d; G[i] = g; Bv[i] = c;
            } else if (!xOdd && rowOdd) {    // p10: R=raw, G=g, B=d
                float g = (2.0f * (ax1y + ax1x) - ax2y - ax2x + 4.0f * c) * 0.125f;
                float d = (2.0f * diag - 1.5f * (ax2y + ax2x) + 6.0f * c) * 0.125f;
                R[i] = c; G[i] = g; Bv[i] = d;
            } else {                         // p11: R=h, G=raw, B=v
                float h = (0.5f * ax2y - diag - ax2x + 4.0f * ax1x + 5.0f * c) * 0.125f;
                float v = (0.5f * ax2x - diag - ax2y + 4.0f * ax1y + 5.0f * c) * 0.125f;
                R[i] = h; G[i] = c; Bv[i] = v;
            }
        }
    };

    dem(w[0], w[1], w[2], cu,       &w[3][4], false, R0, G0, B0);  // even row
    dem(w[1], w[2], w[3], &w[0][4], cd,       true,  R1, G1, B1);  // odd row

    const size_t outb = (size_t)b * 3 * HW;
    int py = gy0 + 2 * rp;
    size_t o = outb + (size_t)py * W + (gx0 + 4 * c4);
    *(float4*)(out + o) = make_float4(clip01(R0[0]), clip01(R0[1]), clip01(R0[2]), clip01(R0[3]));
    *(float4*)(out + o + HW) = make_float4(clip01(G0[0]), clip01(G0[1]), clip01(G0[2]), clip01(G0[3]));
    *(float4*)(out + o + 2 * HW) = make_float4(clip01(B0[0]), clip01(B0[1]), clip01(B0[2]), clip01(B0[3]));
    o += W;
    *(float4*)(out + o) = make_float4(clip01(R1[0]), clip01(R1[1]), clip01(R1[2]), clip01(R1[3]));
    *(float4*)(out + o + HW) = make_float4(clip01(G1[0]), clip01(G1[1]), clip01(G1[2]), clip01(G1[3]));
    *(float4*)(out + o + 2 * HW) = make_float4(clip01(B1[0]), clip01(B1[1]), clip01(B1[2]), clip01(B1[3]));
}

extern "C" void kernel_launch(void* const* d_in, const int* in_sizes, int n_in,
                              void* d_out, int out_size, void* d_ws, size_t ws_size,
                              hipStream_t stream) {
    const float* im    = (const float*)d_in[0];
    const float* yp    = (const float*)d_in[1];
    const float* noise = (const float*)d_in[2];
    float* out = (float*)d_out;

    const int H = 512, W = 512;
    const int B = in_sizes[2] / (H * W);   // noise is (B,1,H,W)

    dim3 grid(W / TX, H / TY, B);
    camera_kernel<<<grid, 256, 0, stream>>>(im, yp, noise, out, H, W);
}